// Round 4
// baseline (710.661 us; speedup 1.0000x reference)
//
#include <hip/hip_runtime.h>

#define VOCAB 50257
#define HID 2048

// K1: out[v] = bias_output[v]; out[VOCAB+j] = input_hidden[current][j] + bias_hidden[j]
__global__ void k_init(const int* __restrict__ cur,
                       const float* __restrict__ ih,
                       const float* __restrict__ bh,
                       const float* __restrict__ bo,
                       float* __restrict__ out) {
    int i = blockIdx.x * blockDim.x + threadIdx.x;
    if (i < VOCAB) out[i] = bo[i];
    if (i < HID) {
        long long row = (long long)(*cur) * HID;
        out[VOCAB + i] = ih[row + i] + bh[i];
    }
}

// K2: partial GEMV prev @ hidden_hidden, atomicAdd into out[VOCAB + col]
// grid: (HID/256 = 8 col-tiles, 32 h-splits of 64 rows), block 256
__global__ void k_hh(const float* __restrict__ prev,
                     const float* __restrict__ hh,
                     float* __restrict__ out) {
    const int col = blockIdx.x * 256 + threadIdx.x;   // always < 2048
    const int h0  = blockIdx.y * 64;
    __shared__ float p[64];
    if (threadIdx.x < 64) p[threadIdx.x] = prev[h0 + threadIdx.x];
    __syncthreads();

    const float* w = hh + (long long)h0 * HID + col;
    float a0 = 0.f, a1 = 0.f, a2 = 0.f, a3 = 0.f;
    #pragma unroll
    for (int i = 0; i < 64; i += 4) {
        a0 = fmaf(p[i + 0], w[0 * HID], a0);
        a1 = fmaf(p[i + 1], w[1 * HID], a1);
        a2 = fmaf(p[i + 2], w[2 * HID], a2);
        a3 = fmaf(p[i + 3], w[3 * HID], a3);
        w += 4 * HID;
    }
    atomicAdd(&out[VOCAB + col], (a0 + a1) + (a2 + a3));
}

// K3: tanh in place on the h_new slot
__global__ void k_tanh(float* __restrict__ out) {
    int i = blockIdx.x * blockDim.x + threadIdx.x;
    if (i < HID) out[VOCAB + i] = tanhf(out[VOCAB + i]);
}

// K4: partial GEMV h_new @ hidden_output, atomicAdd into out[v]
// grid: (ceil(VOCAB/256) = 197 v-tiles, 8 h-splits of 256 rows), block 256
#define HSPLIT 8
#define HCHUNK (HID / HSPLIT)   // 256
__global__ void k_ho(const float* __restrict__ ho,
                     float* __restrict__ out) {
    const int v  = blockIdx.x * 256 + threadIdx.x;
    const int h0 = blockIdx.y * HCHUNK;

    __shared__ float hn[HCHUNK];
    hn[threadIdx.x] = out[VOCAB + h0 + threadIdx.x];  // tanh'd h_new chunk
    __syncthreads();

    if (v >= VOCAB) return;

    const float* w = ho + (long long)h0 * VOCAB + v;
    float a0 = 0.f, a1 = 0.f, a2 = 0.f, a3 = 0.f;
    #pragma unroll 4
    for (int i = 0; i < HCHUNK; i += 4) {
        a0 = fmaf(hn[i + 0], w[0 * VOCAB], a0);
        a1 = fmaf(hn[i + 1], w[1 * VOCAB], a1);
        a2 = fmaf(hn[i + 2], w[2 * VOCAB], a2);
        a3 = fmaf(hn[i + 3], w[3 * VOCAB], a3);
        w += 4 * (long long)VOCAB;
    }
    atomicAdd(&out[v], (a0 + a1) + (a2 + a3));
}

extern "C" void kernel_launch(void* const* d_in, const int* in_sizes, int n_in,
                              void* d_out, int out_size, void* d_ws, size_t ws_size,
                              hipStream_t stream) {
    const int*   cur  = (const int*)  d_in[0];
    const float* prev = (const float*)d_in[1];
    const float* ih   = (const float*)d_in[2];
    const float* hh   = (const float*)d_in[3];
    const float* ho   = (const float*)d_in[4];
    const float* bh   = (const float*)d_in[5];
    const float* bo   = (const float*)d_in[6];
    float* out = (float*)d_out;

    k_init<<<(VOCAB + 255) / 256, 256, 0, stream>>>(cur, ih, bh, bo, out);
    k_hh<<<dim3(HID / 256, 32), 256, 0, stream>>>(prev, hh, out);
    k_tanh<<<(HID + 255) / 256, 256, 0, stream>>>(out);
    k_ho<<<dim3((VOCAB + 255) / 256, HSPLIT), 256, 0, stream>>>(ho, out);
}